// Round 6
// baseline (26.574 us; speedup 1.0000x reference)
//
#include <hip/hip_runtime.h>

#define NATOMS 4096
#define MAXP   32768
#define CUTOFF 5.0f
#define NBLK   1024
#define TPB    256
#define WPB    4               // rows (waves) per block
#define CCH    3               // register-cached 64-wide chunks per row
#define NSLOT  16              // NBLK / 64 state slots per lane

typedef unsigned long long u64;

__device__ __forceinline__ unsigned tag_of(int q) { return 0x9E3779B9u ^ (unsigned)q; }

// Scalar fallback: exact per-row counts for block q's rows (identical FP order).
__device__ int count_rows_scalar(const float* __restrict__ pos,
                                 const int*   __restrict__ batch, int r0) {
#pragma clang fp contract(off)
    int c = 0;
    for (int i = r0; i < r0 + WPB; ++i) {
        const int b = batch[i];
        const float xi = pos[3*i], yi = pos[3*i+1], zi = pos[3*i+2];
        for (int j = i + 1; j < NATOMS; ++j) {
            if (batch[j] != b) break;
            float vx = xi - pos[3*j], vy = yi - pos[3*j+1], vz = zi - pos[3*j+2];
            float d2 = vx*vx + vy*vy + vz*vz;
            if (sqrtf(d2) < CUTOFF) ++c;
        }
    }
    return c;
}

__global__ __launch_bounds__(TPB, 4)
void fused_k(const float* __restrict__ pos,
             const int*   __restrict__ batch,
             u64*         __restrict__ state,
             float*       __restrict__ out) {
#pragma clang fp contract(off)
    const int tid  = threadIdx.x;
    const int p    = blockIdx.x;
    const int w    = tid >> 6;
    const int lane = tid & 63;
    const int i    = p * WPB + w;          // row owned by this wave

    const int b = batch[i];
    const float xi = pos[3*i], yi = pos[3*i+1], zi = pos[3*i+2];

    // ---- Phase A: compute pairs, cache in registers (static indexing) ----
    float cd[CCH], cvx[CCH], cvy[CCH], cvz[CCH];
    int   crank[CCH];
    int   c = 0;
    bool  ended = false;
#pragma unroll
    for (int k = 0; k < CCH; ++k) {
        crank[k] = -1; cd[k] = 0.f; cvx[k] = 0.f; cvy[k] = 0.f; cvz[k] = 0.f;
        int j0 = i + 1 + k * 64;
        if (!ended && j0 < NATOMS) {
            int j = j0 + lane;
            bool in = j < NATOMS;
            int bj = in ? batch[j] : -1;
            bool same = in && (bj == b);
            float vx = 0.f, vy = 0.f, vz = 0.f, d = 0.f;
            bool valid = false;
            if (same) {
                vx = xi - pos[3*j]; vy = yi - pos[3*j+1]; vz = zi - pos[3*j+2];
                float d2 = vx*vx + vy*vy + vz*vz;
                d = sqrtf(d2);
                valid = d < CUTOFF;
            }
            u64 m = __ballot(valid);
            if (valid) {
                crank[k] = c + __popcll(m & ((1ULL << lane) - 1ULL));
                cd[k] = d; cvx[k] = vx; cvy[k] = vy; cvz[k] = vz;
            }
            c += __popcll(m);
            ended = __any(in && (bj != b));
        }
    }
    const int c_cached = c;
    for (int j0 = i + 1 + CCH * 64; j0 < NATOMS && !ended; j0 += 64) {
        int j = j0 + lane;
        bool in = j < NATOMS;
        int bj = in ? batch[j] : -1;
        bool same = in && (bj == b);
        bool valid = false;
        if (same) {
            float vx = xi - pos[3*j], vy = yi - pos[3*j+1], vz = zi - pos[3*j+2];
            valid = sqrtf(vx*vx + vy*vy + vz*vz) < CUTOFF;
        }
        c += __popcll(__ballot(valid));
        ended = __any(in && (bj != b));
    }

    // ---- publish block aggregate ----
    __shared__ int ls[WPB];
    __shared__ int s_pfx, s_total;
    if (lane == 0) ls[w] = c;
    __syncthreads();
    if (tid == 0) {
        unsigned agg = (unsigned)(ls[0] + ls[1] + ls[2] + ls[3]);
        __hip_atomic_store(&state[p], ((u64)tag_of(p) << 32) | agg,
                           __ATOMIC_RELEASE, __HIP_MEMORY_SCOPE_AGENT);
    }

    // ---- wave 0: gather all 1024 aggregates -> prefix(<p) and total ----
    if (w == 0) {
        u64 v[NSLOT];
#pragma unroll
        for (int k = 0; k < NSLOT; ++k)
            v[k] = __hip_atomic_load(&state[lane + 64*k], __ATOMIC_RELAXED,
                                     __HIP_MEMORY_SCOPE_AGENT);
        for (int it = 0; it < 4096; ++it) {
            unsigned bad = 0;
#pragma unroll
            for (int k = 0; k < NSLOT; ++k) {
                int q = lane + 64*k;
                if ((unsigned)(v[k] >> 32) != tag_of(q)) {
                    v[k] = __hip_atomic_load(&state[q], __ATOMIC_RELAXED,
                                             __HIP_MEMORY_SCOPE_AGENT);
                    if ((unsigned)(v[k] >> 32) != tag_of(q)) bad = 1;
                }
            }
            if (!__any(bad)) break;
        }
        // bounded fallback: compute any still-missing aggregate directly
#pragma unroll
        for (int k = 0; k < NSLOT; ++k) {
            int q = lane + 64*k;
            if ((unsigned)(v[k] >> 32) != tag_of(q))
                v[k] = ((u64)tag_of(q) << 32) |
                       (unsigned)count_rows_scalar(pos, batch, q * WPB);
        }
        u64 acc = 0;  // (sum_all << 32) | sum_{q<p}
#pragma unroll
        for (int k = 0; k < NSLOT; ++k) {
            int q = lane + 64*k;
            u64 a = v[k] & 0xffffffffULL;
            acc += (a << 32) | (q < p ? a : 0ULL);
        }
        for (int o = 32; o; o >>= 1) acc += __shfl_down(acc, o);
        if (lane == 0) {
            s_total = (int)(acc >> 32);
            s_pfx   = (int)(acc & 0xffffffffULL);
        }
    }
    __syncthreads();

    const int total = s_total;
    int rowbase = s_pfx;
    for (int r = 0; r < w; ++r) rowbase += ls[r];

    // ---- tail fill [total, MAXP): disjoint from all pair slots ----
    {
        int t = total + p * TPB + tid;
        if (t < MAXP) {
            out[t]            = -1.0f;
            out[MAXP + t]     = -1.0f;
            out[2*MAXP + t]   =  0.0f;
            float* vv = out + 3*MAXP + 3*t;
            vv[0] = 0.f; vv[1] = 0.f; vv[2] = 0.f;
        }
    }

    // ---- Phase B: write cached pairs ----
#pragma unroll
    for (int k = 0; k < CCH; ++k) {
        if (crank[k] >= 0) {
            int slot = rowbase + crank[k];
            if (slot < MAXP) {
                int j = i + 1 + k * 64 + lane;
                out[slot]            = (float)i;
                out[MAXP + slot]     = (float)j;
                out[2*MAXP + slot]   = cd[k];
                float* vv = out + 3*MAXP + 3*slot;
                vv[0] = cvx[k]; vv[1] = cvy[k]; vv[2] = cvz[k];
            }
        }
    }
    // tail chunks beyond register cache: recompute (identical order)
    if (c > c_cached) {
        int slotbase = rowbase + c_cached;
        bool e2 = false;
        for (int j0 = i + 1 + CCH * 64; j0 < NATOMS && !e2; j0 += 64) {
            int j = j0 + lane;
            bool in = j < NATOMS;
            int bj = in ? batch[j] : -1;
            bool same = in && (bj == b);
            float vx = 0.f, vy = 0.f, vz = 0.f, d = 0.f;
            bool valid = false;
            if (same) {
                vx = xi - pos[3*j]; vy = yi - pos[3*j+1]; vz = zi - pos[3*j+2];
                float d2 = vx*vx + vy*vy + vz*vz;
                d = sqrtf(d2);
                valid = d < CUTOFF;
            }
            u64 m = __ballot(valid);
            if (valid) {
                int slot = slotbase + __popcll(m & ((1ULL << lane) - 1ULL));
                if (slot < MAXP) {
                    out[slot]            = (float)i;
                    out[MAXP + slot]     = (float)j;
                    out[2*MAXP + slot]   = d;
                    float* vv = out + 3*MAXP + 3*slot;
                    vv[0] = vx; vv[1] = vy; vv[2] = vz;
                }
            }
            slotbase += __popcll(m);
            e2 = __any(in && (bj != b));
        }
    }
}

extern "C" void kernel_launch(void* const* d_in, const int* in_sizes, int n_in,
                              void* d_out, int out_size, void* d_ws, size_t ws_size,
                              hipStream_t stream) {
    const float* pos   = (const float*)d_in[0];   // [4096,3] f32
    const int*   batch = (const int*)d_in[1];     // [4096] i32 (sorted)
    float* out  = (float*)d_out;                  // 196608 f32 (all outputs)
    u64*   state = (u64*)d_ws;                    // 1024 x u64 publish slots

    fused_k<<<NBLK, TPB, 0, stream>>>(pos, batch, state, out);
}